// Round 1
// baseline (78.522 us; speedup 1.0000x reference)
//
#include <hip/hip_runtime.h>
#include <math.h>

// ---- complex helpers (float32, matches reference complex64) ----
struct c32 { float x, y; };
__device__ inline c32 cmul(c32 a, c32 b){ return {a.x*b.x - a.y*b.y, a.x*b.y + a.y*b.x}; }
__device__ inline c32 cadd(c32 a, c32 b){ return {a.x+b.x, a.y+b.y}; }
__device__ inline c32 conjc(c32 a){ return {a.x, -a.y}; }
__device__ inline c32 cscale(float s, c32 a){ return {s*a.x, s*a.y}; }
__device__ inline c32 cmulni(c32 a){ return {a.y, -a.x}; }   // (-i)*a
__device__ inline c32 cis(float t){ return {cosf(t), sinf(t)}; } // e^{i t}

// Wires: 0..5 data (MSBs), 6..10 hidden (LSBs). index i bit (10-w) <-> wire w.
// psi_b = U |0>_D |b>_H is a PRODUCT of per-wire factors times ZZ diagonal phases.
// S = W rho_H W^dag with W = V6 (x) ... (x) V10;
// rho_h_out[b1,b2] = G * exp(-i(phih(b1)-phih(b2))/2) * S[b1,b2]
// exp_z = (|u0[0]|^2 - |u0[1]|^2) * Re Tr S.
__global__ __launch_bounds__(1024) void pqrnn_kernel(
    const float* __restrict__ x,       // 6
    const float* __restrict__ rho_re,  // 32*32
    const float* __restrict__ rho_im,  // 32*32
    const float* __restrict__ rot,     // 1*11*3
    const float* __restrict__ zz,      // 10
    const float* __restrict__ rw,      // 1
    const float* __restrict__ rb,      // 1
    float* __restrict__ out, int out_size)
{
    __shared__ c32 u[6][2];        // data-wire 2-vectors
    __shared__ c32 V[5][2][2];     // hidden-wire 2x2 unitaries
    __shared__ c32 W[32][32];      // kron of V's
    __shared__ c32 R[32][32];      // rho_H
    __shared__ c32 Xm[32][32];     // W * rho_H
    __shared__ c32 S[32][32];      // W * rho_H * W^dag

    const int tid = threadIdx.x;

    // ---- Phase A: per-wire small unitaries (threads 0..10) ----
    if (tid < 11) {
        const float t0 = rot[tid*3+0], t1 = rot[tid*3+1], t2 = rot[tid*3+2];
        const float c0 = cosf(0.5f*t0), s0 = sinf(0.5f*t0);
        const float c2 = cosf(0.5f*t2), s2 = sinf(0.5f*t2);
        const c32 ez0 = {cosf(0.5f*t1), -sinf(0.5f*t1)};   // e^{-i t1/2}
        const c32 ez1 = conjc(ez0);
        if (tid < 6) {
            // u = RX(t2) RZ(t1) RX(t0) RY(x)|0>
            c32 p0 = {cosf(0.5f*x[tid]), 0.f};
            c32 p1 = {sinf(0.5f*x[tid]), 0.f};
            c32 a0 = cadd(cscale(c0, p0), cscale(s0, cmulni(p1)));
            c32 a1 = cadd(cscale(s0, cmulni(p0)), cscale(c0, p1));
            a0 = cmul(ez0, a0); a1 = cmul(ez1, a1);
            c32 n0 = cadd(cscale(c2, a0), cscale(s2, cmulni(a1)));
            c32 n1 = cadd(cscale(s2, cmulni(a0)), cscale(c2, a1));
            u[tid][0] = n0; u[tid][1] = n1;
        } else {
            // V = RX(t2) RZ(t1) RX(t0), built column by column
            const int h = tid - 6;
            #pragma unroll
            for (int j = 0; j < 2; ++j) {
                c32 p0 = (j == 0) ? c32{c0, 0.f} : c32{0.f, -s0};
                c32 p1 = (j == 0) ? c32{0.f, -s0} : c32{c0, 0.f};
                p0 = cmul(ez0, p0); p1 = cmul(ez1, p1);
                c32 n0 = cadd(cscale(c2, p0), cscale(s2, cmulni(p1)));
                c32 n1 = cadd(cscale(s2, cmulni(p0)), cscale(c2, p1));
                V[h][0][j] = n0; V[h][1][j] = n1;
            }
        }
    }
    __syncthreads();

    const int b1 = tid >> 5, b2 = tid & 31;

    // ---- Phase B: W = kron(V6..V10); load rho_H ----
    {
        c32 w = {1.f, 0.f};
        #pragma unroll
        for (int h = 0; h < 5; ++h) {
            const int r = (b1 >> (4-h)) & 1;
            const int c = (b2 >> (4-h)) & 1;
            w = cmul(w, V[h][r][c]);
        }
        W[b1][b2] = w;
        R[b1][b2] = {rho_re[tid], rho_im[tid]};
    }
    __syncthreads();

    // ---- Phase C: X = W * rho_H ----
    {
        c32 acc = {0.f, 0.f};
        #pragma unroll 8
        for (int k = 0; k < 32; ++k) acc = cadd(acc, cmul(W[b1][k], R[k][b2]));
        Xm[b1][b2] = acc;
    }
    __syncthreads();

    // ---- Phase D: S = X * W^dag ----
    {
        c32 acc = {0.f, 0.f};
        #pragma unroll 8
        for (int k = 0; k < 32; ++k) acc = cadd(acc, cmul(Xm[b1][k], conjc(W[b2][k])));
        S[b1][b2] = acc;
    }
    __syncthreads();

    // ---- Phase E: ZZ phase dressing + output ----
    {
        const float th5 = zz[5];
        const float q0 = u[5][0].x*u[5][0].x + u[5][0].y*u[5][0].y;
        const float q1 = u[5][1].x*u[5][1].x + u[5][1].y*u[5][1].y;
        // hidden ZZ phases: edges (6,7)..(9,10) -> zz[6..9]; wire 6+h <-> bit (4-h)
        const float z14 = 1.f - 2.f*((b1>>4)&1), z13 = 1.f - 2.f*((b1>>3)&1);
        const float z12 = 1.f - 2.f*((b1>>2)&1), z11 = 1.f - 2.f*((b1>>1)&1);
        const float z10 = 1.f - 2.f*(b1&1);
        const float z24 = 1.f - 2.f*((b2>>4)&1), z23 = 1.f - 2.f*((b2>>3)&1);
        const float z22 = 1.f - 2.f*((b2>>2)&1), z21 = 1.f - 2.f*((b2>>1)&1);
        const float z20 = 1.f - 2.f*(b2&1);
        const float ph1 = zz[6]*z14*z13 + zz[7]*z13*z12 + zz[8]*z12*z11 + zz[9]*z11*z10;
        const float ph2 = zz[6]*z24*z23 + zz[7]*z23*z22 + zz[8]*z22*z21 + zz[9]*z21*z20;
        const float dz = z14 - z24;  // z6(b1) - z6(b2), in {0, +-2}
        const c32 G = cadd(cscale(q0, cis(-0.5f*th5*dz)), cscale(q1, cis(0.5f*th5*dz)));
        const c32 ph = cis(-0.5f*(ph1 - ph2));
        const c32 res = cmul(cmul(G, ph), S[b1][b2]);
        if (out_size >= 2049) {            // complex64 flattened: interleaved re,im
            out[1 + 2*tid]     = res.x;
            out[1 + 2*tid + 1] = res.y;
        } else if (out_size >= 1025) {     // fallback: real part only
            out[1 + tid] = res.x;
        }
    }

    // ---- Phase F: exp_z + linear readout (thread 0) ----
    if (tid == 0) {
        float tr = 0.f;
        #pragma unroll 8
        for (int b = 0; b < 32; ++b) tr += S[b][b].x;
        const float pz = (u[0][0].x*u[0][0].x + u[0][0].y*u[0][0].y)
                       - (u[0][1].x*u[0][1].x + u[0][1].y*u[0][1].y);
        const float exp_z = pz * tr;
        const float p1 = 0.5f * (1.f - exp_z);
        out[0] = p1 * rw[0] + rb[0];
    }
}

extern "C" void kernel_launch(void* const* d_in, const int* in_sizes, int n_in,
                              void* d_out, int out_size, void* d_ws, size_t ws_size,
                              hipStream_t stream) {
    const float* x      = (const float*)d_in[0];
    const float* rho_re = (const float*)d_in[1];
    const float* rho_im = (const float*)d_in[2];
    const float* rot    = (const float*)d_in[3];
    const float* zz     = (const float*)d_in[4];
    const float* rw     = (const float*)d_in[5];
    const float* rb     = (const float*)d_in[6];
    float* out = (float*)d_out;
    pqrnn_kernel<<<1, 1024, 0, stream>>>(x, rho_re, rho_im, rot, zz, rw, rb, out, out_size);
}

// Round 2
// 77.698 us; speedup vs baseline: 1.0106x; 1.0106x over previous
//
#include <hip/hip_runtime.h>
#include <math.h>

// ---- complex helpers (float32, matches reference complex64) ----
struct alignas(8) c32 { float x, y; };   // alignas(8) -> ds_read_b64/ds_write_b64
__device__ inline c32 cmul(c32 a, c32 b){ return {a.x*b.x - a.y*b.y, a.x*b.y + a.y*b.x}; }
__device__ inline c32 cadd(c32 a, c32 b){ return {a.x+b.x, a.y+b.y}; }
__device__ inline c32 conjc(c32 a){ return {a.x, -a.y}; }
__device__ inline c32 cscale(float s, c32 a){ return {s*a.x, s*a.y}; }
__device__ inline c32 cmulni(c32 a){ return {a.y, -a.x}; }   // (-i)*a
// fast native trig: v_cos_f32/v_sin_f32 (args here are O(1), error ~1e-6 << 2e-2 threshold)
__device__ inline c32 cis(float t){ return {__cosf(t), __sinf(t)}; } // e^{i t}

// Wires: 0..5 data (MSBs), 6..10 hidden (LSBs). index i bit (10-w) <-> wire w.
// psi_b = U |0>_D |b>_H is a PRODUCT of per-wire factors times ZZ diagonal phases.
// S = W rho_H W^dag with W = V6 (x) ... (x) V10;
// rho_h_out[b1,b2] = G * exp(-i(phih(b1)-phih(b2))/2) * S[b1,b2]
// exp_z = (|u0[0]|^2 - |u0[1]|^2) * Re Tr S.
__global__ __launch_bounds__(1024) void pqrnn_kernel(
    const float* __restrict__ x,       // 6
    const float* __restrict__ rho_re,  // 32*32
    const float* __restrict__ rho_im,  // 32*32
    const float* __restrict__ rot,     // 1*11*3
    const float* __restrict__ zz,      // 10
    const float* __restrict__ rw,      // 1
    const float* __restrict__ rb,      // 1
    float* __restrict__ out, int out_size)
{
    __shared__ c32 u[6][2];        // data-wire 2-vectors
    __shared__ c32 V[5][2][2];     // hidden-wire 2x2 unitaries
    __shared__ c32 W[32][32];      // kron of V's
    __shared__ c32 R[32][32];      // rho_H
    __shared__ c32 Xm[32][32];     // W * rho_H
    __shared__ c32 S[32][32];      // W * rho_H * W^dag

    const int tid = threadIdx.x;

    // ---- Phase A: per-wire small unitaries (threads 0..10) ----
    if (tid < 11) {
        const float t0 = rot[tid*3+0], t1 = rot[tid*3+1], t2 = rot[tid*3+2];
        const float c0 = __cosf(0.5f*t0), s0 = __sinf(0.5f*t0);
        const float c2 = __cosf(0.5f*t2), s2 = __sinf(0.5f*t2);
        const c32 ez0 = {__cosf(0.5f*t1), -__sinf(0.5f*t1)};   // e^{-i t1/2}
        const c32 ez1 = conjc(ez0);
        if (tid < 6) {
            // u = RX(t2) RZ(t1) RX(t0) RY(x)|0>
            c32 p0 = {__cosf(0.5f*x[tid]), 0.f};
            c32 p1 = {__sinf(0.5f*x[tid]), 0.f};
            c32 a0 = cadd(cscale(c0, p0), cscale(s0, cmulni(p1)));
            c32 a1 = cadd(cscale(s0, cmulni(p0)), cscale(c0, p1));
            a0 = cmul(ez0, a0); a1 = cmul(ez1, a1);
            c32 n0 = cadd(cscale(c2, a0), cscale(s2, cmulni(a1)));
            c32 n1 = cadd(cscale(s2, cmulni(a0)), cscale(c2, a1));
            u[tid][0] = n0; u[tid][1] = n1;
        } else {
            // V = RX(t2) RZ(t1) RX(t0), built column by column
            const int h = tid - 6;
            #pragma unroll
            for (int j = 0; j < 2; ++j) {
                c32 p0 = (j == 0) ? c32{c0, 0.f} : c32{0.f, -s0};
                c32 p1 = (j == 0) ? c32{0.f, -s0} : c32{c0, 0.f};
                p0 = cmul(ez0, p0); p1 = cmul(ez1, p1);
                c32 n0 = cadd(cscale(c2, p0), cscale(s2, cmulni(p1)));
                c32 n1 = cadd(cscale(s2, cmulni(p0)), cscale(c2, p1));
                V[h][0][j] = n0; V[h][1][j] = n1;
            }
        }
    }
    __syncthreads();

    const int b1 = tid >> 5, b2 = tid & 31;

    // ---- Phase B: W = kron(V6..V10); load rho_H ----
    {
        c32 w = cmul(V[0][(b1>>4)&1][(b2>>4)&1], V[1][(b1>>3)&1][(b2>>3)&1]);
        w = cmul(w, V[2][(b1>>2)&1][(b2>>2)&1]);
        w = cmul(w, V[3][(b1>>1)&1][(b2>>1)&1]);
        w = cmul(w, V[4][b1&1][b2&1]);
        W[b1][b2] = w;
        R[b1][b2] = {rho_re[tid], rho_im[tid]};
    }
    __syncthreads();

    // ---- Phase C: X = W * rho_H ----
    {
        c32 acc = {0.f, 0.f};
        #pragma unroll
        for (int k = 0; k < 32; ++k) acc = cadd(acc, cmul(W[b1][k], R[k][b2]));
        Xm[b1][b2] = acc;
    }
    __syncthreads();

    // ---- Phase D: S = X * W^dag ----
    {
        c32 acc = {0.f, 0.f};
        #pragma unroll
        for (int k = 0; k < 32; ++k) acc = cadd(acc, cmul(Xm[b1][k], conjc(W[b2][k])));
        S[b1][b2] = acc;
    }
    __syncthreads();

    // ---- Phase E: ZZ phase dressing + output ----
    {
        const float th5 = zz[5];
        const float q0 = u[5][0].x*u[5][0].x + u[5][0].y*u[5][0].y;
        const float q1 = u[5][1].x*u[5][1].x + u[5][1].y*u[5][1].y;
        // hidden ZZ phases: edges (6,7)..(9,10) -> zz[6..9]; wire 6+h <-> bit (4-h)
        const float z14 = 1.f - 2.f*((b1>>4)&1), z13 = 1.f - 2.f*((b1>>3)&1);
        const float z12 = 1.f - 2.f*((b1>>2)&1), z11 = 1.f - 2.f*((b1>>1)&1);
        const float z10 = 1.f - 2.f*(b1&1);
        const float z24 = 1.f - 2.f*((b2>>4)&1), z23 = 1.f - 2.f*((b2>>3)&1);
        const float z22 = 1.f - 2.f*((b2>>2)&1), z21 = 1.f - 2.f*((b2>>1)&1);
        const float z20 = 1.f - 2.f*(b2&1);
        const float ph1 = zz[6]*z14*z13 + zz[7]*z13*z12 + zz[8]*z12*z11 + zz[9]*z11*z10;
        const float ph2 = zz[6]*z24*z23 + zz[7]*z23*z22 + zz[8]*z22*z21 + zz[9]*z21*z20;
        const float dz = z14 - z24;  // z6(b1) - z6(b2), in {0, +-2}
        const c32 G = cadd(cscale(q0, cis(-0.5f*th5*dz)), cscale(q1, cis(0.5f*th5*dz)));
        const c32 ph = cis(-0.5f*(ph1 - ph2));
        const c32 res = cmul(cmul(G, ph), S[b1][b2]);
        if (out_size >= 2049) {            // complex64 flattened: interleaved re,im
            out[1 + 2*tid]     = res.x;
            out[1 + 2*tid + 1] = res.y;
        } else if (out_size >= 1025) {     // fallback: real part only
            out[1 + tid] = res.x;
        }
    }

    // ---- Phase F: exp_z + linear readout (thread 0) ----
    if (tid == 0) {
        float tr = 0.f;
        #pragma unroll
        for (int b = 0; b < 32; ++b) tr += S[b][b].x;
        const float pz = (u[0][0].x*u[0][0].x + u[0][0].y*u[0][0].y)
                       - (u[0][1].x*u[0][1].x + u[0][1].y*u[0][1].y);
        const float exp_z = pz * tr;
        const float p1 = 0.5f * (1.f - exp_z);
        out[0] = p1 * rw[0] + rb[0];
    }
}

extern "C" void kernel_launch(void* const* d_in, const int* in_sizes, int n_in,
                              void* d_out, int out_size, void* d_ws, size_t ws_size,
                              hipStream_t stream) {
    const float* x      = (const float*)d_in[0];
    const float* rho_re = (const float*)d_in[1];
    const float* rho_im = (const float*)d_in[2];
    const float* rot    = (const float*)d_in[3];
    const float* zz     = (const float*)d_in[4];
    const float* rw     = (const float*)d_in[5];
    const float* rb     = (const float*)d_in[6];
    float* out = (float*)d_out;
    pqrnn_kernel<<<1, 1024, 0, stream>>>(x, rho_re, rho_im, rot, zz, rw, rb, out, out_size);
}